// Round 1
// baseline (102.873 us; speedup 1.0000x reference)
//
#include <hip/hip_runtime.h>
#include <math.h>

#define N_ 256
#define C_ 100
#define D_ 512
// SCALE = 3.0, so ||Xn_row|| = ||Pn_row|| = 3

__device__ inline float waveReduceSum(float v) {
    #pragma unroll
    for (int off = 32; off > 0; off >>= 1) v += __shfl_xor(v, off, 64);
    return v;
}
__device__ inline float waveReduceMax(float v) {
    #pragma unroll
    for (int off = 32; off > 0; off >>= 1) v = fmaxf(v, __shfl_xor(v, off, 64));
    return v;
}
__device__ inline float clip1(float x) { return fminf(fmaxf(x, -1.0f), 1.0f); }

// One block (128 threads) per row; rows 0..255 = X, 256..355 = proxies.
__global__ void normalize_kernel(const float* __restrict__ X,
                                 const float* __restrict__ P,
                                 float* __restrict__ Xn,
                                 float* __restrict__ Pn) {
    int r = blockIdx.x;
    const float* src; float* dst;
    if (r < N_) { src = X + (size_t)r * D_;        dst = Xn + (size_t)r * D_; }
    else        { src = P + (size_t)(r - N_) * D_; dst = Pn + (size_t)(r - N_) * D_; }
    int t = threadIdx.x;  // 128 threads * float4 = 512 floats
    float4 v = ((const float4*)src)[t];
    float ss = v.x*v.x + v.y*v.y + v.z*v.z + v.w*v.w;
    __shared__ float sdata[2];
    float wsum = waveReduceSum(ss);
    int w = t >> 6, lane = t & 63;
    if (lane == 0) sdata[w] = wsum;
    __syncthreads();
    float tot = sdata[0] + sdata[1];
    float scale = 3.0f / fmaxf(sqrtf(tot), 1e-12f);
    float4 o; o.x = v.x*scale; o.y = v.y*scale; o.z = v.z*scale; o.w = v.w*scale;
    ((float4*)dst)[t] = o;
}

// IP = Xn @ Pn^T : one wave per (i,p) dot product. Grid 6400 x 256 (4 waves).
__global__ void ip_kernel(const float* __restrict__ Xn,
                          const float* __restrict__ Pn,
                          float* __restrict__ IP) {
    int wid = blockIdx.x * 4 + (threadIdx.x >> 6);   // [0, 25600)
    int lane = threadIdx.x & 63;
    int i = wid / C_;
    int p = wid - i * C_;
    const float4* a = (const float4*)(Xn + (size_t)i * D_);
    const float4* b = (const float4*)(Pn + (size_t)p * D_);
    float acc = 0.0f;
    #pragma unroll
    for (int k = 0; k < 2; ++k) {
        float4 av = a[lane + 64*k], bv = b[lane + 64*k];
        acc += av.x*bv.x + av.y*bv.y + av.z*bv.z + av.w*bv.w;
    }
    acc = waveReduceSum(acc);
    if (lane == 0) IP[wid] = acc;
}

// One wave per pair (i1,i2) over the full 256x256 grid, skip i2<=i1 and same-class.
// Grid 16384 x 256 threads (4 waves/block). Per-block partial sum/count.
__global__ void pair_kernel(const float* __restrict__ Xn,
                            const float* __restrict__ IP,
                            const int* __restrict__ T,
                            float* __restrict__ psum,
                            float* __restrict__ pcnt) {
    int w = threadIdx.x >> 6, lane = threadIdx.x & 63;
    int pid = blockIdx.x * 4 + w;          // [0, 65536)
    int i1 = pid >> 8, i2 = pid & 255;
    float contrib = 0.0f, ccount = 0.0f;
    if (i2 > i1) {
        int t1 = T[i1], t2 = T[i2];
        if (t1 != t2) {
            // Gram entry G[i1,i2] = Xn[i1] . Xn[i2] (in-wave 512-dot)
            const float4* a = (const float4*)(Xn + (size_t)i1 * D_);
            const float4* b = (const float4*)(Xn + (size_t)i2 * D_);
            float g = 0.0f;
            #pragma unroll
            for (int k = 0; k < 2; ++k) {
                float4 av = a[lane + 64*k], bv = b[lane + 64*k];
                g += av.x*bv.x + av.y*bv.y + av.z*bv.z + av.w*bv.w;
            }
            g = waveReduceSum(g);

            const float* ip1 = IP + (size_t)i1 * C_;
            const float* ip2 = IP + (size_t)i2 * C_;
            float X1P1 = clip1(ip1[t1]);
            float X1P2 = clip1(ip1[t2]);
            float X2P1 = clip1(ip2[t1]);
            float X2P2 = clip1(ip2[t2]);
            float num = X2P2 - X2P1;
            float den = num + X1P1 - X1P2;
            float lam = fminf(fmaxf(num / den, 0.3f), 0.7f);
            float oml = 1.0f - lam;

            float wn2 = 9.0f * (lam*lam + oml*oml) + 2.0f * lam * oml * g;
            float s = 3.0f / fmaxf(sqrtf(fmaxf(wn2, 0.0f)), 1e-12f);
            float s2 = 2.0f * s;

            // logits e_p = 2 * s * (lam*IP[i1,p] + (1-lam)*IP[i2,p]); p = lane, lane+64
            float e_a = s2 * (lam * ip1[lane] + oml * ip2[lane]);
            bool vb = lane < (C_ - 64);
            float e_b = vb ? s2 * (lam * ip1[lane+64] + oml * ip2[lane+64]) : -INFINITY;
            float mx = waveReduceMax(fmaxf(e_a, e_b));
            float sum = expf(e_a - mx) + (vb ? expf(e_b - mx) : 0.0f);
            sum = waveReduceSum(sum);
            float LSE = mx + logf(sum);

            float ec1 = (t1 < 64) ? __shfl(e_a, t1, 64) : __shfl(e_b, t1 - 64, 64);
            float ec2 = (t2 < 64) ? __shfl(e_a, t2, 64) : __shfl(e_b, t2 - 64, 64);
            contrib = LSE - lam * ec1 - oml * ec2;
            ccount = 1.0f;
        }
    }
    __shared__ float ssum[4], scnt[4];
    if (lane == 0) { ssum[w] = contrib; scnt[w] = ccount; }
    __syncthreads();
    if (threadIdx.x == 0) {
        psum[blockIdx.x] = ssum[0] + ssum[1] + ssum[2] + ssum[3];
        pcnt[blockIdx.x] = scnt[0] + scnt[1] + scnt[2] + scnt[3];
    }
}

// Real-sample loss: one wave per row i. Grid 64 x 256.
__global__ void real_kernel(const float* __restrict__ IP,
                            const int* __restrict__ T,
                            float* __restrict__ loss_real) {
    int w = threadIdx.x >> 6, lane = threadIdx.x & 63;
    int i = blockIdx.x * 4 + w;            // [0, 256)
    const float* ip = IP + (size_t)i * C_;
    float e_a = 2.0f * ip[lane];
    bool vb = lane < (C_ - 64);
    float e_b = vb ? 2.0f * ip[lane+64] : -INFINITY;
    float mx = waveReduceMax(fmaxf(e_a, e_b));
    float sum = expf(e_a - mx) + (vb ? expf(e_b - mx) : 0.0f);
    sum = waveReduceSum(sum);
    float LSE = mx + logf(sum);
    if (lane == 0) {
        int t = T[i];
        loss_real[i] = LSE - 2.0f * ip[t];
    }
}

// Final reduce: 1 block x 256 threads.
__global__ void finalize_kernel(const float* __restrict__ psum,
                                const float* __restrict__ pcnt,
                                const float* __restrict__ loss_real,
                                float* __restrict__ out) {
    int t = threadIdx.x;
    float a = 0.0f, c = 0.0f;
    for (int k = t; k < 16384; k += 256) { a += psum[k]; c += pcnt[k]; }
    a += loss_real[t];
    float ra = waveReduceSum(a), rc = waveReduceSum(c);
    __shared__ float s1[4], s2[4];
    int w = t >> 6, lane = t & 63;
    if (lane == 0) { s1[w] = ra; s2[w] = rc; }
    __syncthreads();
    if (t == 0) {
        float tot = s1[0] + s1[1] + s1[2] + s1[3];
        float cnt = s2[0] + s2[1] + s2[2] + s2[3];
        out[0] = tot / ((float)N_ + cnt);
    }
}

extern "C" void kernel_launch(void* const* d_in, const int* in_sizes, int n_in,
                              void* d_out, int out_size, void* d_ws, size_t ws_size,
                              hipStream_t stream) {
    const float* X = (const float*)d_in[0];   // (256, 512) f32
    const float* P = (const float*)d_in[1];   // (100, 512) f32
    const int*   T = (const int*)d_in[2];     // (256,) i32
    // d_in[3] = indices, unused
    float* ws = (float*)d_ws;
    float* Xn        = ws;                    // 131072
    float* Pn        = ws + 131072;           // 51200
    float* IP        = ws + 182272;           // 25600
    float* loss_real = ws + 207872;           // 256
    float* psum      = ws + 208128;           // 16384
    float* pcnt      = ws + 224512;           // 16384  (total 240896 floats < 1 MB)
    float* out = (float*)d_out;

    normalize_kernel<<<356, 128, 0, stream>>>(X, P, Xn, Pn);
    ip_kernel<<<6400, 256, 0, stream>>>(Xn, Pn, IP);
    pair_kernel<<<16384, 256, 0, stream>>>(Xn, IP, T, psum, pcnt);
    real_kernel<<<64, 256, 0, stream>>>(IP, T, loss_real);
    finalize_kernel<<<1, 256, 0, stream>>>(psum, pcnt, loss_real, out);
}